// Round 1
// baseline (1920.875 us; speedup 1.0000x reference)
//
#include <hip/hip_runtime.h>

typedef unsigned short u16;
typedef unsigned int   u32;

// ---- bf16 <-> f32 helpers (bit-level, RNE) ----
__device__ __forceinline__ float bf2f(u16 h)  { return __uint_as_float(((u32)h) << 16); }
__device__ __forceinline__ float bflo(u32 w)  { return __uint_as_float(w << 16); }
__device__ __forceinline__ float bfhi(u32 w)  { return __uint_as_float(w & 0xffff0000u); }
__device__ __forceinline__ u16   f2bf(float f) {
    u32 u = __float_as_uint(f);
    u32 r = (u + 0x7fffu + ((u >> 16) & 1u)) >> 16;
    return (u16)r;
}

constexpr int HW  = 112;
constexpr int C   = 128;
constexpr int NH  = 4;
constexpr int SSZ = 3;
constexpr int NT  = 49;   // tokens per 7x7 window

constexpr int XS_STRIDE  = 136;  // halfwords per token row (x window / pv buffer), 16B-aligned rows
constexpr int QKV_STRIDE = 36;   // halfwords per (which,head,row) 32-vector, 8B-aligned rows
constexpr int ATT_STRIDE = 50;   // halfwords per attn row

__global__ __launch_bounds__(256, 2)
void swin_fused(const float* __restrict__ x,
                const float* __restrict__ mask,
                const float* __restrict__ qkv_w,
                const float* __restrict__ qkv_b,
                const float* __restrict__ proj_w,
                const float* __restrict__ proj_b,
                const float* __restrict__ rpb,
                const int*   __restrict__ rel_index,
                float* __restrict__ out)
{
    __shared__ __align__(16) u16 xs[NT * XS_STRIDE];            // 13,328 B ; reused as pv after stage 2
    __shared__ __align__(16) u16 qkv_s[12 * NT * QKV_STRIDE];   // 42,336 B : [which(3)][head(4)][row(49)][36]
    __shared__ __align__(16) u16 attn_s[NH * NT * ATT_STRIDE];  // 19,600 B
    __shared__ float rsums[NH * NT];                            //    784 B

    const int tid = threadIdx.x;
    const int bid = blockIdx.x;
    const int b   = bid >> 8;        // image
    const int wi  = bid & 255;       // window within image
    const int wh  = wi >> 4, wwc = wi & 15;

    // ---------- stage 1: load rolled x window -> LDS (bf16) ----------
    for (int idx = tid; idx < NT * C; idx += 256) {
        int t = idx >> 7, c = idx & 127;
        int tr = t / 7, tc = t - tr * 7;
        int hs = wh  * 7 + tr + SSZ; if (hs >= HW) hs -= HW;
        int cs = wwc * 7 + tc + SSZ; if (cs >= HW) cs -= HW;
        float v = x[((b * HW + hs) * HW + cs) * C + c];
        xs[t * XS_STRIDE + c] = f2bf(v);
    }
    __syncthreads();

    // ---------- stage 2: QKV GEMM (49x128 @ 128x384), 8 outputs/thread ----------
    const float scale = 0.17677669529663687f;  // 32^-0.5
    for (int g = tid; g < NT * 48; g += 256) {
        int r  = g % 49;
        int o0 = (g / 49) << 3;
        float acc[8];
#pragma unroll
        for (int j = 0; j < 8; ++j) acc[j] = 0.f;
        for (int k = 0; k < 128; k += 8) {
            uint4 xv = *(const uint4*)&xs[r * XS_STRIDE + k];
            float xf[8] = { bflo(xv.x), bfhi(xv.x), bflo(xv.y), bfhi(xv.y),
                            bflo(xv.z), bfhi(xv.z), bflo(xv.w), bfhi(xv.w) };
#pragma unroll
            for (int j = 0; j < 8; ++j) {
                const float4* wp = (const float4*)&qkv_w[(o0 + j) * 128 + k];
                float4 w0 = wp[0], w1 = wp[1];
                acc[j] += w0.x * xf[0] + w0.y * xf[1] + w0.z * xf[2] + w0.w * xf[3];
                acc[j] += w1.x * xf[4] + w1.y * xf[5] + w1.z * xf[6] + w1.w * xf[7];
            }
        }
#pragma unroll
        for (int j = 0; j < 8; ++j) {
            int o = o0 + j;
            float a = acc[j] + qkv_b[o];
            int which = o >> 7, ch = o & 127;
            int hh = ch >> 5, d = ch & 31;
            if (which == 0) a *= scale;           // pre-scale q
            qkv_s[((which * 4 + hh) * NT + r) * QKV_STRIDE + d] = f2bf(a);
        }
    }
    __syncthreads();

    // ---------- stage 3: scores + softmax, one thread per (head,row) ----------
    if (tid < NH * NT) {
        int hh = tid / NT, r = tid - hh * NT;
        float q[32];
        const u16* qp = &qkv_s[(hh * NT + r) * QKV_STRIDE];
#pragma unroll
        for (int d = 0; d < 32; d += 2) {
            u32 wq = *(const u32*)&qp[d];
            q[d] = bflo(wq); q[d + 1] = bfhi(wq);
        }
        float smax = -1e30f;
        const float* mrow = &mask[(wi * NT + r) * NT];
        const int*   rrow = &rel_index[r * NT];
        u16* arow = &attn_s[(hh * NT + r) * ATT_STRIDE];
        for (int m = 0; m < 49; ++m) {
            const u16* kp = &qkv_s[((4 + hh) * NT + m) * QKV_STRIDE];
            float s = 0.f;
#pragma unroll
            for (int d = 0; d < 32; d += 2) {
                u32 wk = *(const u32*)&kp[d];
                s += q[d] * bflo(wk);
                s += q[d + 1] * bfhi(wk);
            }
            s += rpb[rrow[m] * 4 + hh] + mrow[m];
            smax = fmaxf(smax, s);
            arow[m] = f2bf(s);
        }
        float sum = 0.f;
        for (int m = 0; m < 49; ++m) {
            float p = __expf(bf2f(arow[m]) - smax);
            sum += p;
            arow[m] = f2bf(p);
        }
        rsums[hh * NT + r] = 1.f / sum;
    }
    __syncthreads();

    // ---------- stage 4: PV (probs @ V), 4 outputs/thread, write pv into xs ----------
    for (int u = tid; u < NT * 32; u += 256) {
        int r  = u >> 5;
        int uq = u & 31;
        int hh = uq >> 3;
        int d0 = (uq & 7) << 2;
        const u16* pr = &attn_s[(hh * NT + r) * ATT_STRIDE];
        const u16* vr = &qkv_s[((8 + hh) * NT) * QKV_STRIDE + d0];
        float a0 = 0.f, a1 = 0.f, a2 = 0.f, a3 = 0.f;
        for (int m = 0; m < 49; ++m) {
            float p = bf2f(pr[m]);
            uint2 vv = *(const uint2*)&vr[m * QKV_STRIDE];
            a0 += p * bflo(vv.x); a1 += p * bfhi(vv.x);
            a2 += p * bflo(vv.y); a3 += p * bfhi(vv.y);
        }
        float rs = rsums[hh * NT + r];
        int c0 = hh * 32 + d0;
        u32 lo = (u32)f2bf(a0 * rs) | ((u32)f2bf(a1 * rs) << 16);
        u32 hi = (u32)f2bf(a2 * rs) | ((u32)f2bf(a3 * rs) << 16);
        *(uint2*)&xs[r * XS_STRIDE + c0] = make_uint2(lo, hi);
    }
    __syncthreads();

    // ---------- stage 5: proj (pv @ proj_w.T + b), coalesced store with un-roll ----------
    for (int idx = tid; idx < NT * C; idx += 256) {
        int r = idx >> 7, c = idx & 127;
        const float4* wp = (const float4*)&proj_w[c * 128];
        float acc = 0.f;
        for (int k = 0; k < 128; k += 8) {
            uint4 pvv = *(const uint4*)&xs[r * XS_STRIDE + k];
            float4 w0 = wp[k >> 2], w1 = wp[(k >> 2) + 1];
            acc += w0.x * bflo(pvv.x) + w0.y * bfhi(pvv.x);
            acc += w0.z * bflo(pvv.y) + w0.w * bfhi(pvv.y);
            acc += w1.x * bflo(pvv.z) + w1.y * bfhi(pvv.z);
            acc += w1.z * bflo(pvv.w) + w1.w * bfhi(pvv.w);
        }
        acc += proj_b[c];
        int tr = r / 7, tc = r - tr * 7;
        int hs = wh  * 7 + tr + SSZ; if (hs >= HW) hs -= HW;
        int cs = wwc * 7 + tc + SSZ; if (cs >= HW) cs -= HW;
        out[((b * HW + hs) * HW + cs) * C + c] = acc;
    }
}

extern "C" void kernel_launch(void* const* d_in, const int* in_sizes, int n_in,
                              void* d_out, int out_size, void* d_ws, size_t ws_size,
                              hipStream_t stream) {
    (void)in_sizes; (void)n_in; (void)out_size; (void)d_ws; (void)ws_size;
    const float* x      = (const float*)d_in[0];
    const float* mask   = (const float*)d_in[1];
    const float* qkv_w  = (const float*)d_in[2];
    const float* qkv_b  = (const float*)d_in[3];
    const float* proj_w = (const float*)d_in[4];
    const float* proj_b = (const float*)d_in[5];
    const float* rpb    = (const float*)d_in[6];
    const int*   rel    = (const int*)d_in[7];
    float* out = (float*)d_out;

    swin_fused<<<dim3(2048), dim3(256), 0, stream>>>(
        x, mask, qkv_w, qkv_b, proj_w, proj_b, rpb, rel, out);
}

// Round 2
// 160.710 us; speedup vs baseline: 11.9525x; 11.9525x over previous
//
#include <hip/hip_runtime.h>

typedef unsigned short u16;
typedef unsigned int   u32;
typedef __attribute__((ext_vector_type(8))) short bf16x8;
typedef __attribute__((ext_vector_type(4))) float f32x4;

__device__ __forceinline__ float bf2f(u16 h) { return __uint_as_float(((u32)h) << 16); }
__device__ __forceinline__ u16 f2bf(float f) {
    u32 u = __float_as_uint(f);
    return (u16)((u + 0x7fffu + ((u >> 16) & 1u)) >> 16);
}

constexpr int QK_STR = 40;   // halfwords per q/k row  (mult of 8 for b128, banks spread)
constexpr int VT_STR = 72;   // halfwords per vT row
constexpr int P_STR  = 72;   // halfwords per P row
constexpr int O_STR  = 136;  // halfwords per o_s row

// workspace (u16 elems): [0,49152) qkv_w bf16 ; [49152,65536) proj_w bf16 ;
//                        [65536,131072) fused bias+mask bf16 [cls4][h4][64][64]
__global__ void prep_kernel(const float* __restrict__ qkv_w,
                            const float* __restrict__ proj_w,
                            const float* __restrict__ mask,
                            const float* __restrict__ rpb,
                            const int*   __restrict__ rel,
                            u16* __restrict__ ws)
{
    int i = blockIdx.x * 256 + threadIdx.x;
    if (i < 49152) ws[i] = f2bf(qkv_w[i]);
    if (i < 16384) ws[49152 + i] = f2bf(proj_w[i]);
    if (i < 65536) {
        int m = i & 63, r = (i >> 6) & 63, h = (i >> 12) & 3, cls = i >> 14;
        float v;
        if (m >= 49)      v = -30000.f;   // kill padded K-tokens: exp underflows to exact 0
        else if (r >= 49) v = 0.f;        // padded Q-rows: value irrelevant, keep finite
        else {
            int rep = ((cls & 2) ? 240 : 0) + ((cls & 1) ? 15 : 0);  // representative window
            v = rpb[rel[r * 49 + m] * 4 + h] + mask[(rep * 49 + r) * 49 + m];
        }
        ws[65536 + i] = f2bf(v);
    }
}

__global__ __launch_bounds__(512, 2)
void swin_mfma(const float* __restrict__ x,
               const float* __restrict__ qkv_b,
               const float* __restrict__ proj_b,
               const u16*   __restrict__ wqkv,
               const u16*   __restrict__ wproj,
               const u16*   __restrict__ fused,
               float* __restrict__ out)
{
    __shared__ u16 q_s[4 * 64 * QK_STR];   // 20480 B
    __shared__ u16 k_s[4 * 64 * QK_STR];   // 20480 B
    __shared__ u16 vT_s[4 * 32 * VT_STR];  // 18432 B
    __shared__ u16 p_s[8 * 16 * P_STR];    // 18432 B (per-wave P rows)
    __shared__ u16 o_s[64 * O_STR];        // 17408 B

    const int tid  = threadIdx.x;
    const int w    = tid >> 6;          // wave 0..7
    const int lane = tid & 63;
    const int lr   = lane & 15;         // frag row/col index
    const int lg   = lane >> 4;         // frag k-group 0..3
    const int bid  = blockIdx.x;
    const int b    = bid >> 8;
    const int wi   = bid & 255;
    const int wh   = wi >> 4, ww = wi & 15;
    const int cls  = ((wh == 15) ? 2 : 0) | ((ww == 15) ? 1 : 0);

    // ---------------- stage 1: QKV GEMM, x read as A-frags from global ----------------
    bf16x8 a[4][4];
#pragma unroll
    for (int mt2 = 0; mt2 < 4; ++mt2) {
        int tok = mt2 * 16 + lr;
        int tr = tok / 7, tc = tok - tr * 7;
        int hs = wh * 7 + tr + 3; if (hs >= 112) hs -= 112;
        int cs = ww * 7 + tc + 3; if (cs >= 112) cs -= 112;
        int xbase = ((b * 112 + hs) * 112 + cs) * 128;
        bool valid = tok < 49;
#pragma unroll
        for (int kt = 0; kt < 4; ++kt) {
            bf16x8 f = {0, 0, 0, 0, 0, 0, 0, 0};
            if (valid) {
                const float4* xp = (const float4*)&x[xbase + kt * 32 + lg * 8];
                float4 x0 = xp[0], x1 = xp[1];
                f[0] = f2bf(x0.x); f[1] = f2bf(x0.y); f[2] = f2bf(x0.z); f[3] = f2bf(x0.w);
                f[4] = f2bf(x1.x); f[5] = f2bf(x1.y); f[6] = f2bf(x1.z); f[7] = f2bf(x1.w);
            }
            a[mt2][kt] = f;
        }
    }

#pragma unroll
    for (int t = 0; t < 3; ++t) {
        int n0 = w * 48 + t * 16;                 // output-channel tile base (uniform per wave)
        bf16x8 bw[4];
#pragma unroll
        for (int kt = 0; kt < 4; ++kt)
            bw[kt] = *(const bf16x8*)&wqkv[(n0 + lr) * 128 + kt * 32 + lg * 8];
        float bias = qkv_b[n0 + lr];
        int which = n0 >> 7;                      // 0=q 1=k 2=v (uniform)
        int h = (n0 & 127) >> 5;                  // head (uniform)
        int d = (n0 & 31) + lr;                   // dim within head
#pragma unroll
        for (int mt2 = 0; mt2 < 4; ++mt2) {
            f32x4 acc = {0.f, 0.f, 0.f, 0.f};
#pragma unroll
            for (int kt = 0; kt < 4; ++kt)
                acc = __builtin_amdgcn_mfma_f32_16x16x32_bf16(a[mt2][kt], bw[kt], acc, 0, 0, 0);
            if (which == 0) {
#pragma unroll
                for (int j = 0; j < 4; ++j)
                    q_s[(h * 64 + mt2 * 16 + lg * 4 + j) * QK_STR + d] =
                        f2bf((acc[j] + bias) * 0.17677669529663687f);
            } else if (which == 1) {
#pragma unroll
                for (int j = 0; j < 4; ++j)
                    k_s[(h * 64 + mt2 * 16 + lg * 4 + j) * QK_STR + d] = f2bf(acc[j] + bias);
            } else {
                ushort4 pk;
                pk.x = f2bf(acc[0] + bias); pk.y = f2bf(acc[1] + bias);
                pk.z = f2bf(acc[2] + bias); pk.w = f2bf(acc[3] + bias);
                *(ushort4*)&vT_s[(h * 32 + d) * VT_STR + mt2 * 16 + lg * 4] = pk;  // V transposed
            }
        }
    }
    __syncthreads();  // the only block-wide barrier before proj

    // ---------------- stage 2: attention; wave -> (M-tile, head-pair) ----------------
    const int mt = w & 3, hp = w >> 2;
    float invs[2][4];
#pragma unroll
    for (int hl = 0; hl < 2; ++hl) {
        int h = hp * 2 + hl;
        bf16x8 aq = *(const bf16x8*)&q_s[(h * 64 + mt * 16 + lr) * QK_STR + lg * 8];
        f32x4 sc[4];
#pragma unroll
        for (int nt = 0; nt < 4; ++nt) {
            bf16x8 bk = *(const bf16x8*)&k_s[(h * 64 + nt * 16 + lr) * QK_STR + lg * 8];
            f32x4 z = {0.f, 0.f, 0.f, 0.f};
            sc[nt] = __builtin_amdgcn_mfma_f32_16x16x32_bf16(aq, bk, z, 0, 0, 0);
        }
        float s[4][4];
        const u16* ft = &fused[((cls * 4 + h) * 64 + mt * 16) * 64];
#pragma unroll
        for (int j = 0; j < 4; ++j)
#pragma unroll
            for (int nt = 0; nt < 4; ++nt)
                s[nt][j] = sc[nt][j] + bf2f(ft[(lg * 4 + j) * 64 + nt * 16 + lr]);
#pragma unroll
        for (int j = 0; j < 4; ++j) {
            float mx = fmaxf(fmaxf(s[0][j], s[1][j]), fmaxf(s[2][j], s[3][j]));
            mx = fmaxf(mx, __shfl_xor(mx, 1));
            mx = fmaxf(mx, __shfl_xor(mx, 2));
            mx = fmaxf(mx, __shfl_xor(mx, 4));
            mx = fmaxf(mx, __shfl_xor(mx, 8));
            float p0 = __expf(s[0][j] - mx), p1 = __expf(s[1][j] - mx);
            float p2 = __expf(s[2][j] - mx), p3 = __expf(s[3][j] - mx);
            float sm = p0 + p1 + p2 + p3;
            sm += __shfl_xor(sm, 1);
            sm += __shfl_xor(sm, 2);
            sm += __shfl_xor(sm, 4);
            sm += __shfl_xor(sm, 8);
            invs[hl][j] = 1.f / sm;   // sum >= 1 always (max term is 1)
            u16* pr = &p_s[(w * 16 + lg * 4 + j) * P_STR];
            pr[lr]      = f2bf(p0);
            pr[16 + lr] = f2bf(p1);
            pr[32 + lr] = f2bf(p2);
            pr[48 + lr] = f2bf(p3);
        }
        // PV: A = P (own rows), B = vT
        bf16x8 ap0 = *(const bf16x8*)&p_s[(w * 16 + lr) * P_STR + lg * 8];
        bf16x8 ap1 = *(const bf16x8*)&p_s[(w * 16 + lr) * P_STR + 32 + lg * 8];
#pragma unroll
        for (int nt = 0; nt < 2; ++nt) {
            bf16x8 bv0 = *(const bf16x8*)&vT_s[(h * 32 + nt * 16 + lr) * VT_STR + lg * 8];
            bf16x8 bv1 = *(const bf16x8*)&vT_s[(h * 32 + nt * 16 + lr) * VT_STR + 32 + lg * 8];
            f32x4 z = {0.f, 0.f, 0.f, 0.f};
            f32x4 o = __builtin_amdgcn_mfma_f32_16x16x32_bf16(ap0, bv0, z, 0, 0, 0);
            o = __builtin_amdgcn_mfma_f32_16x16x32_bf16(ap1, bv1, o, 0, 0, 0);
#pragma unroll
            for (int j = 0; j < 4; ++j)
                o_s[(mt * 16 + lg * 4 + j) * O_STR + h * 32 + nt * 16 + lr] =
                    f2bf(o[j] * invs[hl][j]);
        }
    }
    __syncthreads();  // o_s columns cross heads written by two waves per row-tile

    // ---------------- stage 3: proj; wave -> (M-tile mt, N-half hp) ----------------
    bf16x8 ao[4];
#pragma unroll
    for (int kt = 0; kt < 4; ++kt)
        ao[kt] = *(const bf16x8*)&o_s[(mt * 16 + lr) * O_STR + kt * 32 + lg * 8];
    int obase[4];
#pragma unroll
    for (int j = 0; j < 4; ++j) {
        int tok = mt * 16 + lg * 4 + j;
        if (tok < 49) {
            int tr = tok / 7, tc = tok - tr * 7;
            int hs = wh * 7 + tr + 3; if (hs >= 112) hs -= 112;
            int cs = ww * 7 + tc + 3; if (cs >= 112) cs -= 112;
            obase[j] = ((b * 112 + hs) * 112 + cs) * 128;
        } else obase[j] = -1;
    }
#pragma unroll
    for (int tn = 0; tn < 4; ++tn) {
        int n0 = (hp * 4 + tn) * 16;
        bf16x8 bw[4];
#pragma unroll
        for (int kt = 0; kt < 4; ++kt)
            bw[kt] = *(const bf16x8*)&wproj[(n0 + lr) * 128 + kt * 32 + lg * 8];
        f32x4 acc = {0.f, 0.f, 0.f, 0.f};
#pragma unroll
        for (int kt = 0; kt < 4; ++kt)
            acc = __builtin_amdgcn_mfma_f32_16x16x32_bf16(ao[kt], bw[kt], acc, 0, 0, 0);
        float bias = proj_b[n0 + lr];
#pragma unroll
        for (int j = 0; j < 4; ++j)
            if (obase[j] >= 0) out[obase[j] + n0 + lr] = acc[j] + bias;
    }
}

extern "C" void kernel_launch(void* const* d_in, const int* in_sizes, int n_in,
                              void* d_out, int out_size, void* d_ws, size_t ws_size,
                              hipStream_t stream) {
    (void)in_sizes; (void)n_in; (void)out_size; (void)ws_size;
    const float* x      = (const float*)d_in[0];
    const float* mask   = (const float*)d_in[1];
    const float* qkv_w  = (const float*)d_in[2];
    const float* qkv_b  = (const float*)d_in[3];
    const float* proj_w = (const float*)d_in[4];
    const float* proj_b = (const float*)d_in[5];
    const float* rpb    = (const float*)d_in[6];
    const int*   rel    = (const int*)d_in[7];
    float* out = (float*)d_out;

    u16* ws16 = (u16*)d_ws;
    prep_kernel<<<dim3(256), dim3(256), 0, stream>>>(qkv_w, proj_w, mask, rpb, rel, ws16);
    swin_mfma<<<dim3(2048), dim3(512), 0, stream>>>(
        x, qkv_b, proj_b, ws16, ws16 + 49152, ws16 + 65536, out);
}

// Round 3
// 160.707 us; speedup vs baseline: 11.9527x; 1.0000x over previous
//
#include <hip/hip_runtime.h>

typedef unsigned short u16;
typedef unsigned int   u32;
typedef __attribute__((ext_vector_type(8))) short bf16x8;
typedef __attribute__((ext_vector_type(4))) float f32x4;

__device__ __forceinline__ float bf2f(u16 h) { return __uint_as_float(((u32)h) << 16); }
__device__ __forceinline__ u16 f2bf(float f) {
    u32 u = __float_as_uint(f);
    return (u16)((u + 0x7fffu + ((u >> 16) & 1u)) >> 16);
}

constexpr int QK_STR = 40;   // halfwords per q/k row  (mult of 8 for b128, banks spread)
constexpr int VT_STR = 72;   // halfwords per vT row
constexpr int P_STR  = 72;   // halfwords per P row
constexpr int O_STR  = 136;  // halfwords per o_s row

// workspace (u16 elems): [0,49152) qkv_w bf16 ; [49152,65536) proj_w bf16 ;
//                        [65536,131072) fused bias+mask bf16 [cls4][h4][64][64]
__global__ void prep_kernel(const float* __restrict__ qkv_w,
                            const float* __restrict__ proj_w,
                            const float* __restrict__ mask,
                            const float* __restrict__ rpb,
                            const int*   __restrict__ rel,
                            u16* __restrict__ ws)
{
    int i = blockIdx.x * 256 + threadIdx.x;
    if (i < 49152) ws[i] = f2bf(qkv_w[i]);
    if (i < 16384) ws[49152 + i] = f2bf(proj_w[i]);
    if (i < 65536) {
        int m = i & 63, r = (i >> 6) & 63, h = (i >> 12) & 3, cls = i >> 14;
        float v;
        if (m >= 49)      v = -30000.f;   // kill padded K-tokens: exp underflows to exact 0
        else if (r >= 49) v = 0.f;        // padded Q-rows: value irrelevant, keep finite
        else {
            int rep = ((cls & 2) ? 240 : 0) + ((cls & 1) ? 15 : 0);  // representative window
            v = rpb[rel[r * 49 + m] * 4 + h] + mask[(rep * 49 + r) * 49 + m];
        }
        ws[65536 + i] = f2bf(v);
    }
}

__global__ __launch_bounds__(512, 2)
void swin_mfma(const float* __restrict__ x,
               const float* __restrict__ qkv_b,
               const float* __restrict__ proj_b,
               const u16*   __restrict__ wqkv,
               const u16*   __restrict__ wproj,
               const u16*   __restrict__ fused,
               float* __restrict__ out)
{
    __shared__ u16 q_s[4 * 64 * QK_STR];   // 20480 B
    __shared__ u16 k_s[4 * 64 * QK_STR];   // 20480 B
    __shared__ u16 vT_s[4 * 32 * VT_STR];  // 18432 B
    __shared__ u16 p_s[8 * 16 * P_STR];    // 18432 B (per-wave P rows)
    __shared__ u16 o_s[64 * O_STR];        // 17408 B

    const int tid  = threadIdx.x;
    const int w    = tid >> 6;          // wave 0..7
    const int lane = tid & 63;
    const int lr   = lane & 15;         // frag row/col index
    const int lg   = lane >> 4;         // frag k-group 0..3
    const int bid  = blockIdx.x;
    const int b    = bid >> 8;
    const int wi   = bid & 255;
    const int wh   = wi >> 4, ww = wi & 15;
    const int cls  = ((wh == 15) ? 2 : 0) | ((ww == 15) ? 1 : 0);

    // ---------------- stage 1: QKV GEMM, x read as A-frags from global ----------------
    bf16x8 a[4][4];
#pragma unroll
    for (int mt2 = 0; mt2 < 4; ++mt2) {
        int tok = mt2 * 16 + lr;
        int tr = tok / 7, tc = tok - tr * 7;
        int hs = wh * 7 + tr + 3; if (hs >= 112) hs -= 112;
        int cs = ww * 7 + tc + 3; if (cs >= 112) cs -= 112;
        int xbase = ((b * 112 + hs) * 112 + cs) * 128;
        bool valid = tok < 49;
#pragma unroll
        for (int kt = 0; kt < 4; ++kt) {
            bf16x8 f = {0, 0, 0, 0, 0, 0, 0, 0};
            if (valid) {
                const float4* xp = (const float4*)&x[xbase + kt * 32 + lg * 8];
                float4 x0 = xp[0], x1 = xp[1];
                f[0] = f2bf(x0.x); f[1] = f2bf(x0.y); f[2] = f2bf(x0.z); f[3] = f2bf(x0.w);
                f[4] = f2bf(x1.x); f[5] = f2bf(x1.y); f[6] = f2bf(x1.z); f[7] = f2bf(x1.w);
            }
            a[mt2][kt] = f;
        }
    }

#pragma unroll
    for (int t = 0; t < 3; ++t) {
        int n0 = w * 48 + t * 16;                 // output-channel tile base (uniform per wave)
        bf16x8 bw[4];
#pragma unroll
        for (int kt = 0; kt < 4; ++kt)
            bw[kt] = *(const bf16x8*)&wqkv[(n0 + lr) * 128 + kt * 32 + lg * 8];
        float bias = qkv_b[n0 + lr];
        int which = n0 >> 7;                      // 0=q 1=k 2=v (uniform)
        int h = (n0 & 127) >> 5;                  // head (uniform)
        int d = (n0 & 31) + lr;                   // dim within head
#pragma unroll
        for (int mt2 = 0; mt2 < 4; ++mt2) {
            f32x4 acc = {0.f, 0.f, 0.f, 0.f};
#pragma unroll
            for (int kt = 0; kt < 4; ++kt)
                acc = __builtin_amdgcn_mfma_f32_16x16x32_bf16(a[mt2][kt], bw[kt], acc, 0, 0, 0);
            if (which == 0) {
#pragma unroll
                for (int j = 0; j < 4; ++j)
                    q_s[(h * 64 + mt2 * 16 + lg * 4 + j) * QK_STR + d] =
                        f2bf((acc[j] + bias) * 0.17677669529663687f);
            } else if (which == 1) {
#pragma unroll
                for (int j = 0; j < 4; ++j)
                    k_s[(h * 64 + mt2 * 16 + lg * 4 + j) * QK_STR + d] = f2bf(acc[j] + bias);
            } else {
                ushort4 pk;
                pk.x = f2bf(acc[0] + bias); pk.y = f2bf(acc[1] + bias);
                pk.z = f2bf(acc[2] + bias); pk.w = f2bf(acc[3] + bias);
                *(ushort4*)&vT_s[(h * 32 + d) * VT_STR + mt2 * 16 + lg * 4] = pk;  // V transposed
            }
        }
    }
    __syncthreads();  // the only block-wide barrier before proj

    // ---------------- stage 2: attention; wave -> (M-tile, head-pair) ----------------
    const int mt = w & 3, hp = w >> 2;
    float invs[2][4];
#pragma unroll
    for (int hl = 0; hl < 2; ++hl) {
        int h = hp * 2 + hl;
        bf16x8 aq = *(const bf16x8*)&q_s[(h * 64 + mt * 16 + lr) * QK_STR + lg * 8];
        f32x4 sc[4];
#pragma unroll
        for (int nt = 0; nt < 4; ++nt) {
            bf16x8 bk = *(const bf16x8*)&k_s[(h * 64 + nt * 16 + lr) * QK_STR + lg * 8];
            f32x4 z = {0.f, 0.f, 0.f, 0.f};
            sc[nt] = __builtin_amdgcn_mfma_f32_16x16x32_bf16(aq, bk, z, 0, 0, 0);
        }
        float s[4][4];
        const u16* ft = &fused[((cls * 4 + h) * 64 + mt * 16) * 64];
#pragma unroll
        for (int j = 0; j < 4; ++j)
#pragma unroll
            for (int nt = 0; nt < 4; ++nt)
                s[nt][j] = sc[nt][j] + bf2f(ft[(lg * 4 + j) * 64 + nt * 16 + lr]);
#pragma unroll
        for (int j = 0; j < 4; ++j) {
            float mx = fmaxf(fmaxf(s[0][j], s[1][j]), fmaxf(s[2][j], s[3][j]));
            mx = fmaxf(mx, __shfl_xor(mx, 1));
            mx = fmaxf(mx, __shfl_xor(mx, 2));
            mx = fmaxf(mx, __shfl_xor(mx, 4));
            mx = fmaxf(mx, __shfl_xor(mx, 8));
            float p0 = __expf(s[0][j] - mx), p1 = __expf(s[1][j] - mx);
            float p2 = __expf(s[2][j] - mx), p3 = __expf(s[3][j] - mx);
            float sm = p0 + p1 + p2 + p3;
            sm += __shfl_xor(sm, 1);
            sm += __shfl_xor(sm, 2);
            sm += __shfl_xor(sm, 4);
            sm += __shfl_xor(sm, 8);
            invs[hl][j] = 1.f / sm;   // sum >= 1 always (max term is 1)
            u16* pr = &p_s[(w * 16 + lg * 4 + j) * P_STR];
            pr[lr]      = f2bf(p0);
            pr[16 + lr] = f2bf(p1);
            pr[32 + lr] = f2bf(p2);
            pr[48 + lr] = f2bf(p3);
        }
        // PV: A = P (own rows), B = vT
        bf16x8 ap0 = *(const bf16x8*)&p_s[(w * 16 + lr) * P_STR + lg * 8];
        bf16x8 ap1 = *(const bf16x8*)&p_s[(w * 16 + lr) * P_STR + 32 + lg * 8];
#pragma unroll
        for (int nt = 0; nt < 2; ++nt) {
            bf16x8 bv0 = *(const bf16x8*)&vT_s[(h * 32 + nt * 16 + lr) * VT_STR + lg * 8];
            bf16x8 bv1 = *(const bf16x8*)&vT_s[(h * 32 + nt * 16 + lr) * VT_STR + 32 + lg * 8];
            f32x4 z = {0.f, 0.f, 0.f, 0.f};
            f32x4 o = __builtin_amdgcn_mfma_f32_16x16x32_bf16(ap0, bv0, z, 0, 0, 0);
            o = __builtin_amdgcn_mfma_f32_16x16x32_bf16(ap1, bv1, o, 0, 0, 0);
#pragma unroll
            for (int j = 0; j < 4; ++j)
                o_s[(mt * 16 + lg * 4 + j) * O_STR + h * 32 + nt * 16 + lr] =
                    f2bf(o[j] * invs[hl][j]);
        }
    }
    __syncthreads();  // o_s columns cross heads written by two waves per row-tile

    // ---------------- stage 3: proj; wave -> (M-tile mt, N-half hp) ----------------
    bf16x8 ao[4];
#pragma unroll
    for (int kt = 0; kt < 4; ++kt)
        ao[kt] = *(const bf16x8*)&o_s[(mt * 16 + lr) * O_STR + kt * 32 + lg * 8];
    int obase[4];
#pragma unroll
    for (int j = 0; j < 4; ++j) {
        int tok = mt * 16 + lg * 4 + j;
        if (tok < 49) {
            int tr = tok / 7, tc = tok - tr * 7;
            int hs = wh * 7 + tr + 3; if (hs >= 112) hs -= 112;
            int cs = ww * 7 + tc + 3; if (cs >= 112) cs -= 112;
            obase[j] = ((b * 112 + hs) * 112 + cs) * 128;
        } else obase[j] = -1;
    }
#pragma unroll
    for (int tn = 0; tn < 4; ++tn) {
        int n0 = (hp * 4 + tn) * 16;
        bf16x8 bw[4];
#pragma unroll
        for (int kt = 0; kt < 4; ++kt)
            bw[kt] = *(const bf16x8*)&wproj[(n0 + lr) * 128 + kt * 32 + lg * 8];
        f32x4 acc = {0.f, 0.f, 0.f, 0.f};
#pragma unroll
        for (int kt = 0; kt < 4; ++kt)
            acc = __builtin_amdgcn_mfma_f32_16x16x32_bf16(ao[kt], bw[kt], acc, 0, 0, 0);
        float bias = proj_b[n0 + lr];
#pragma unroll
        for (int j = 0; j < 4; ++j)
            if (obase[j] >= 0) out[obase[j] + n0 + lr] = acc[j] + bias;
    }
}

extern "C" void kernel_launch(void* const* d_in, const int* in_sizes, int n_in,
                              void* d_out, int out_size, void* d_ws, size_t ws_size,
                              hipStream_t stream) {
    (void)in_sizes; (void)n_in; (void)out_size; (void)ws_size;
    const float* x      = (const float*)d_in[0];
    const float* mask   = (const float*)d_in[1];
    const float* qkv_w  = (const float*)d_in[2];
    const float* qkv_b  = (const float*)d_in[3];
    const float* proj_w = (const float*)d_in[4];
    const float* proj_b = (const float*)d_in[5];
    const float* rpb    = (const float*)d_in[6];
    const int*   rel    = (const int*)d_in[7];
    float* out = (float*)d_out;

    u16* ws16 = (u16*)d_ws;
    prep_kernel<<<dim3(256), dim3(256), 0, stream>>>(qkv_w, proj_w, mask, rpb, rel, ws16);
    swin_mfma<<<dim3(2048), dim3(512), 0, stream>>>(
        x, qkv_b, proj_b, ws16, ws16 + 49152, ws16 + 65536, out);
}